// Round 8
// baseline (144.797 us; speedup 1.0000x reference)
//
#include <hip/hip_runtime.h>
#include <math.h>

// Problem constants (fixed by setup_inputs)
#define B   16
#define L   512
#define H   768
#define HV4 192      // H/4 float4s per row
#define S1  32
#define S2  128
#define NS  8
#define M   4
#define CH  16       // L-chunk rows per partial block
#define NCHUNK 32    // L / CH
#define NROW 512     // B*S1 explanation rows

// ---------------------------------------------------------------------------
// K1 (fused): 1536 blocks, 384 threads (two 192-thread halves). [R7-validated,
// byte-identical]
//   bid <  512 : row_cls mean over ballot-compacted rows of expl_h1+expl_h2
//   bid < 1024 : sent partial sums over 16-row chunks
//   else       : sel span partial sums over 16-row chunks
// ---------------------------------------------------------------------------
__global__ __launch_bounds__(384)
void k_pool(const float* __restrict__ e1, const float* __restrict__ e2,
            const int* __restrict__ am,
            const float* __restrict__ s1, const float* __restrict__ s2,
            const int* __restrict__ iam,
            const float* __restrict__ hs, const int* __restrict__ st_,
            const int* __restrict__ en_,
            float* __restrict__ row_cls,
            float* __restrict__ sp_part, float* __restrict__ sp_cnt,
            float* __restrict__ sel_part, float* __restrict__ sel_cnt) {
  const int bid = blockIdx.x;
  const int t = threadIdx.x;
  const int half = t / 192;       // wave-uniform (waves 0-2 vs 3-5)
  const int tt = t % 192;
  __shared__ int   idxL[S2];
  __shared__ int   cntS;
  __shared__ float4 pf[192];      // half-1 partials for the combine

  if (bid < 512) {
    const int i = bid;
    if (t < 64) {
      const int m0 = am[i * S2 + t];
      const int m1 = am[i * S2 + 64 + t];
      const unsigned long long b0 = __ballot(m0 != 0);
      const unsigned long long b1 = __ballot(m1 != 0);
      const int c0 = (int)__popcll(b0);
      if (m0) idxL[(int)__popcll(b0 & ((1ULL << t) - 1))] = t;
      if (m1) idxL[c0 + (int)__popcll(b1 & ((1ULL << t) - 1))] = 64 + t;
      if (t == 0) cntS = c0 + (int)__popcll(b1);
    }
    __syncthreads();
    const int cnt = cntS;
    const int cntH = (cnt + 1 - half) >> 1;   // half0 ceil, half1 floor
    const float4* p1 = (const float4*)e1 + (size_t)i * (S2 * HV4) + tt;
    const float4* p2 = (const float4*)e2 + (size_t)i * (S2 * HV4) + tt;
    float ax = 0.f, ay = 0.f, az = 0.f, aw = 0.f;
    int kk = 0;
    for (; kk + 3 < cntH; kk += 4) {
      const int j0 = idxL[2 * kk + half];
      const int j1 = idxL[2 * (kk + 1) + half];
      const int j2 = idxL[2 * (kk + 2) + half];
      const int j3 = idxL[2 * (kk + 3) + half];
      float4 a0 = p1[j0 * HV4], b0 = p2[j0 * HV4];
      float4 a1 = p1[j1 * HV4], b1 = p2[j1 * HV4];
      float4 a2 = p1[j2 * HV4], b2 = p2[j2 * HV4];
      float4 a3 = p1[j3 * HV4], b3 = p2[j3 * HV4];
      ax += (a0.x + b0.x) + (a1.x + b1.x) + (a2.x + b2.x) + (a3.x + b3.x);
      ay += (a0.y + b0.y) + (a1.y + b1.y) + (a2.y + b2.y) + (a3.y + b3.y);
      az += (a0.z + b0.z) + (a1.z + b1.z) + (a2.z + b2.z) + (a3.z + b3.z);
      aw += (a0.w + b0.w) + (a1.w + b1.w) + (a2.w + b2.w) + (a3.w + b3.w);
    }
    for (; kk < cntH; ++kk) {
      const int j = idxL[2 * kk + half];
      float4 a = p1[j * HV4], b = p2[j * HV4];
      ax += a.x + b.x; ay += a.y + b.y; az += a.z + b.z; aw += a.w + b.w;
    }
    if (half == 1) { float4 o; o.x = ax; o.y = ay; o.z = az; o.w = aw; pf[tt] = o; }
    __syncthreads();
    if (half == 0) {
      const float inv = 1.f / (float)cnt;
      float4 o = pf[tt];
      o.x = (ax + o.x) * inv; o.y = (ay + o.y) * inv;
      o.z = (az + o.z) * inv; o.w = (aw + o.w) * inv;
      ((float4*)row_cls)[(size_t)i * HV4 + tt] = o;
    }
  } else if (bid < 1024) {
    const int blk = bid - 512;
    const int b = blk >> 5, c = blk & 31;
    if (t < 64) {
      const int m = (t < CH) ? iam[b * L + c * CH + t] : 0;
      const unsigned long long bm = __ballot(m != 0);
      if (m) idxL[(int)__popcll(bm & ((1ULL << t) - 1))] = t;
      if (t == 0) { const int cc = (int)__popcll(bm); cntS = cc; sp_cnt[blk] = (float)cc; }
    }
    __syncthreads();
    const int cnt = cntS;
    const int cntH = (cnt + 1 - half) >> 1;
    const float4* p1 = (const float4*)s1 + ((size_t)b * L + c * CH) * HV4 + tt;
    const float4* p2 = (const float4*)s2 + ((size_t)b * L + c * CH) * HV4 + tt;
    float ax = 0.f, ay = 0.f, az = 0.f, aw = 0.f;
    int kk = 0;
    for (; kk + 1 < cntH; kk += 2) {
      const int l0 = idxL[2 * kk + half];
      const int l1 = idxL[2 * (kk + 1) + half];
      float4 a0 = p1[l0 * HV4], b0 = p2[l0 * HV4];
      float4 a1 = p1[l1 * HV4], b1 = p2[l1 * HV4];
      ax += (a0.x + b0.x) + (a1.x + b1.x);
      ay += (a0.y + b0.y) + (a1.y + b1.y);
      az += (a0.z + b0.z) + (a1.z + b1.z);
      aw += (a0.w + b0.w) + (a1.w + b1.w);
    }
    for (; kk < cntH; ++kk) {
      const int l = idxL[2 * kk + half];
      float4 a = p1[l * HV4], b = p2[l * HV4];
      ax += a.x + b.x; ay += a.y + b.y; az += a.z + b.z; aw += a.w + b.w;
    }
    if (half == 1) { float4 o; o.x = ax; o.y = ay; o.z = az; o.w = aw; pf[tt] = o; }
    __syncthreads();
    if (half == 0) {
      float4 o = pf[tt];
      o.x += ax; o.y += ay; o.z += az; o.w += aw;
      ((float4*)sp_part)[(size_t)blk * HV4 + tt] = o;
    }
  } else {
    const int blk = bid - 1024;
    const int b = blk >> 5, c = blk & 31;
    const int st = st_[b], en = en_[b];
    const int lo = st > c * CH ? st : c * CH;
    const int hi = en < c * CH + CH ? en : c * CH + CH;
    const float4* p = (const float4*)hs + (size_t)b * L * HV4 + tt;
    float ax = 0.f, ay = 0.f, az = 0.f, aw = 0.f;
    for (int l = lo + half; l < hi; l += 2) {   // this half's rows, in-bounds
      float4 a0 = p[l * HV4];
      ax += a0.x; ay += a0.y; az += a0.z; aw += a0.w;
    }
    if (half == 1) { float4 o; o.x = ax; o.y = ay; o.z = az; o.w = aw; pf[tt] = o; }
    __syncthreads();
    if (half == 0) {
      float4 o = pf[tt];
      o.x += ax; o.y += ay; o.z += az; o.w += aw;
      ((float4*)sel_part)[(size_t)blk * HV4 + tt] = o;
      if (tt == 0) sel_cnt[blk] = (float)(hi > lo ? hi - lo : 0);
    }
  }
}

// ---------------------------------------------------------------------------
// K2: Z = row_cls @ W_t^T and U = row_cls @ W_attn^T  (both 512x768).
// Exploits linearity: y = sum_m w*(cls@W_t^T)+b_t and sim = sp.(cls@W_attn^T),
// so the whole attention+transform chain collapses into per-b finals (K3).
// Grid 768 blocks = 2 mats x 12 h-tiles x 32 row-tiles(16 rows). 256 thr.
// Pattern = validated k_transform: rc rows staged in LDS (48 KiB -> 3
// blocks/CU), each lane streams its W row (h = ht*64+lane) as float4 from L2,
// 4 row-accumulators share each W load (rows w*4..w*4+3, wave-uniform ->
// LDS broadcast).
// ---------------------------------------------------------------------------
__global__ __launch_bounds__(256)
void k_zu(const float* __restrict__ rc, const float* __restrict__ W_t,
          const float* __restrict__ W_attn,
          float* __restrict__ Z, float* __restrict__ U) {
  const int bid = blockIdx.x;
  const int mat = bid / 384;
  const int rr = bid - mat * 384;
  const int ht = rr >> 5;        // 0..11
  const int rt = rr & 31;        // 0..31
  const float* W = mat ? W_attn : W_t;
  float* O = mat ? U : Z;
  const int t = threadIdx.x;
  __shared__ float4 rcL[16 * HV4];   // 48 KiB
  const float4* src = (const float4*)rc + (size_t)(rt * 16) * HV4;
  for (int idx = t; idx < 16 * HV4; idx += 256) rcL[idx] = src[idx];
  __syncthreads();
  const int lane = t & 63, w = t >> 6;
  const int h = ht * 64 + lane;
  const float4* wr = (const float4*)(W + (size_t)h * H);
  const float4* r0 = rcL + (w * 4 + 0) * HV4;
  const float4* r1 = rcL + (w * 4 + 1) * HV4;
  const float4* r2 = rcL + (w * 4 + 2) * HV4;
  const float4* r3 = rcL + (w * 4 + 3) * HV4;
  float a0 = 0.f, a1 = 0.f, a2 = 0.f, a3 = 0.f;
  #pragma unroll 4
  for (int d = 0; d < HV4; ++d) {
    const float4 wv = wr[d];
    const float4 p0 = r0[d], p1 = r1[d], p2 = r2[d], p3 = r3[d];
    a0 += wv.x * p0.x + wv.y * p0.y + wv.z * p0.z + wv.w * p0.w;
    a1 += wv.x * p1.x + wv.y * p1.y + wv.z * p1.z + wv.w * p1.w;
    a2 += wv.x * p2.x + wv.y * p2.y + wv.z * p2.z + wv.w * p2.w;
    a3 += wv.x * p3.x + wv.y * p3.y + wv.z * p3.z + wv.w * p3.w;
  }
  const int row = rt * 16 + w * 4;
  O[(size_t)(row + 0) * H + h] = a0;
  O[(size_t)(row + 1) * H + h] = a1;
  O[(size_t)(row + 2) * H + h] = a2;
  O[(size_t)(row + 3) * H + h] = a3;
}

// ---------------------------------------------------------------------------
// K3: per-b finale. Grid B=16 blocks, 256 threads, ~4 barriers.
//   sp/sel combines -> sel-LN (in-reg, shfl) -> sims = sp.U rows (shfl) ->
//   ragged softmax -> y rows from Z (+b_t) -> row-LN stats (shfl) -> cosine.
// All inputs L2-resident (~0.4 MB/block).
// ---------------------------------------------------------------------------
__global__ __launch_bounds__(256)
void k_final(const float* __restrict__ sp_part, const float* __restrict__ sp_cnt,
             const float* __restrict__ sel_part, const float* __restrict__ sel_cnt,
             const float* __restrict__ U, const float* __restrict__ Z,
             const int* __restrict__ extra_index, const float* __restrict__ b_t,
             const float* __restrict__ gamma_t, const float* __restrict__ beta_t,
             const float* __restrict__ gamma_s, const float* __restrict__ beta_s,
             float* __restrict__ out) {
  const int b = blockIdx.x, t = threadIdx.x;
  const int lane = t & 63, w = t >> 6;
  __shared__ float red8[8];
  __shared__ float wred[S1 * 4];
  __shared__ float w2L[S1];
  __shared__ float redS[NS * 4];
  __shared__ float redQ[NS * 4];

  // --- combines (32 L-chunks each)
  float csp = 0.f, csel = 0.f;
  for (int c = 0; c < NCHUNK; ++c) {
    csp += sp_cnt[b * NCHUNK + c];
    csel += sel_cnt[b * NCHUNK + c];
  }
  const float invp = 1.f / csp, invs = 1.f / csel;
  float spv[3], selv[3];
  #pragma unroll
  for (int k = 0; k < 3; ++k) {
    const int h = t + k * 256;
    float a = 0.f, s = 0.f;
    for (int c = 0; c < NCHUNK; ++c) {
      a += sp_part[((size_t)b * NCHUNK + c) * H + h];
      s += sel_part[((size_t)b * NCHUNK + c) * H + h];
    }
    spv[k] = a * invp;
    selv[k] = s * invs;
  }
  // --- sel LayerNorm (single-pass sum/sumsq, 1 barrier)
  {
    float s = selv[0] + selv[1] + selv[2];
    float ss = selv[0] * selv[0] + selv[1] * selv[1] + selv[2] * selv[2];
    #pragma unroll
    for (int off = 32; off > 0; off >>= 1) {
      s += __shfl_down(s, off);
      ss += __shfl_down(ss, off);
    }
    if (lane == 0) { red8[w] = s; red8[4 + w] = ss; }
  }
  __syncthreads();
  float sl[3];
  {
    const float S = red8[0] + red8[1] + red8[2] + red8[3];
    const float Q = red8[4] + red8[5] + red8[6] + red8[7];
    const float mu = S / (float)H;
    const float var = Q / (float)H - mu * mu;
    const float rstd = rsqrtf(var + 1e-12f);
    #pragma unroll
    for (int k = 0; k < 3; ++k) {
      const int h = t + k * 256;
      sl[k] = (selv[k] - mu) * rstd * gamma_s[h] + beta_s[h];
    }
  }
  // --- sims: sim[i] = sp . U[b*32+i, :]
  for (int i = 0; i < S1; ++i) {
    const float* ur = U + (size_t)(b * S1 + i) * H;
    float a = spv[0] * ur[t] + spv[1] * ur[t + 256] + spv[2] * ur[t + 512];
    #pragma unroll
    for (int off = 32; off > 0; off >>= 1) a += __shfl_down(a, off);
    if (lane == 0) wred[i * 4 + w] = a;
  }
  __syncthreads();
  // --- ragged softmax per group n (threads 0..7)
  if (t < NS) {
    const int vid = extra_index[b * NS + t];
    const float scale = 0.036084391824351615f;  // 1/sqrt(768)
    float x[M], mx = -1e30f;
    #pragma unroll
    for (int m = 0; m < M; ++m) {
      const int i = t * M + m;
      const float sim = (wred[i * 4] + wred[i * 4 + 1] + wred[i * 4 + 2] + wred[i * 4 + 3]) * scale;
      x[m] = (m < vid) ? sim : -1e30f;
      mx = fmaxf(mx, x[m]);
    }
    float s = 0.f, e[M];
    #pragma unroll
    for (int m = 0; m < M; ++m) { e[m] = expf(x[m] - mx); s += e[m]; }
    #pragma unroll
    for (int m = 0; m < M; ++m) w2L[t * M + m] = e[m] / s;
  }
  __syncthreads();
  // --- y rows from Z (+b_t), single-pass stats
  float bt[3], g[3], be[3];
  #pragma unroll
  for (int k = 0; k < 3; ++k) {
    const int h = t + k * 256;
    bt[k] = b_t[h]; g[k] = gamma_t[h]; be[k] = beta_t[h];
  }
  float v[NS][3];
  for (int n = 0; n < NS; ++n) {
    const float w0 = w2L[n * M + 0], w1 = w2L[n * M + 1];
    const float w2v = w2L[n * M + 2], w3 = w2L[n * M + 3];
    const float* z0 = Z + (size_t)(b * S1 + n * M + 0) * H;
    const float* z1 = Z + (size_t)(b * S1 + n * M + 1) * H;
    const float* z2 = Z + (size_t)(b * S1 + n * M + 2) * H;
    const float* z3 = Z + (size_t)(b * S1 + n * M + 3) * H;
    float s = 0.f, ss = 0.f;
    #pragma unroll
    for (int k = 0; k < 3; ++k) {
      const int h = t + k * 256;
      const float y = bt[k] + w0 * z0[h] + w1 * z1[h] + w2v * z2[h] + w3 * z3[h];
      v[n][k] = y; s += y; ss += y * y;
    }
    #pragma unroll
    for (int off = 32; off > 0; off >>= 1) {
      s += __shfl_down(s, off);
      ss += __shfl_down(ss, off);
    }
    if (lane == 0) { redS[n * 4 + w] = s; redQ[n * 4 + w] = ss; }
  }
  __syncthreads();
  // --- row LN + cosine score
  float S[3] = {0.f, 0.f, 0.f}, SS[3] = {0.f, 0.f, 0.f};
  for (int n = 0; n < NS; ++n) {
    const float Sn = redS[n * 4] + redS[n * 4 + 1] + redS[n * 4 + 2] + redS[n * 4 + 3];
    const float Qn = redQ[n * 4] + redQ[n * 4 + 1] + redQ[n * 4 + 2] + redQ[n * 4 + 3];
    const float mu = Sn / (float)H;
    const float var = Qn / (float)H - mu * mu;
    const float rstd = rsqrtf(var + 1e-12f);
    #pragma unroll
    for (int k = 0; k < 3; ++k) {
      const float c = (v[n][k] - mu) * rstd * g[k] + be[k];
      S[k] += c; SS[k] += c * c;
    }
  }
  #pragma unroll
  for (int k = 0; k < 3; ++k) {
    const int h = t + k * 256;
    const float n1 = 2.8284271247461903f * fabsf(sl[k]);  // sqrt(8)*|sel|
    const float n2 = sqrtf(SS[k]);
    out[(size_t)b * H + h] = sl[k] * S[k] / (fmaxf(n1, 1e-8f) * fmaxf(n2, 1e-8f));
  }
}

// ---------------------------------------------------------------------------
extern "C" void kernel_launch(void* const* d_in, const int* in_sizes, int n_in,
                              void* d_out, int out_size, void* d_ws, size_t ws_size,
                              hipStream_t stream) {
  const float* hidden_states = (const float*)d_in[0];
  const float* sent_h1       = (const float*)d_in[1];
  const float* sent_h2       = (const float*)d_in[2];
  const int*   attention_mask= (const int*)  d_in[3];
  const float* expl_h1       = (const float*)d_in[4];
  const float* expl_h2       = (const float*)d_in[5];
  const int*   extra_am      = (const int*)  d_in[6];
  const int*   extra_index   = (const int*)  d_in[7];
  const int*   extra_start   = (const int*)  d_in[8];
  const int*   extra_end     = (const int*)  d_in[9];
  const float* W_attn        = (const float*)d_in[10];
  const float* W_t           = (const float*)d_in[11];
  const float* b_t           = (const float*)d_in[12];
  const float* gamma_t       = (const float*)d_in[13];
  const float* beta_t        = (const float*)d_in[14];
  const float* gamma_s       = (const float*)d_in[15];
  const float* beta_s        = (const float*)d_in[16];
  float* out = (float*)d_out;

  float* ws = (float*)d_ws;
  float* row_cls  = ws;                        // 512*768
  float* sp_part  = row_cls + NROW * H;        // 512*768
  float* sp_cnt   = sp_part + NROW * H;        // 512
  float* sel_part = sp_cnt + 512;              // 512*768
  float* sel_cnt  = sel_part + NROW * H;       // 512
  float* Zb       = sel_cnt + 512;             // 512*768
  float* Ub       = Zb + NROW * H;             // 512*768

  k_pool<<<1536, 384, 0, stream>>>(expl_h1, expl_h2, extra_am,
                                   sent_h1, sent_h2, attention_mask,
                                   hidden_states, extra_start, extra_end,
                                   row_cls, sp_part, sp_cnt, sel_part, sel_cnt);
  k_zu<<<768, 256, 0, stream>>>(row_cls, W_t, W_attn, Zb, Ub);
  k_final<<<B, 256, 0, stream>>>(sp_part, sp_cnt, sel_part, sel_cnt, Ub, Zb,
                                 extra_index, b_t, gamma_t, beta_t,
                                 gamma_s, beta_s, out);
}

// Round 9
// 102.601 us; speedup vs baseline: 1.4113x; 1.4113x over previous
//
#include <hip/hip_runtime.h>
#include <math.h>

// Problem constants (fixed by setup_inputs)
#define B   16
#define L   512
#define H   768
#define HV4 192      // H/4 float4s per row
#define S1  32
#define S2  128
#define NS  8
#define M   4
#define CH  16       // L-chunk rows per partial block
#define NCHUNK 32    // L / CH

// ---------------------------------------------------------------------------
// K1 (fused): 1536 blocks, 384 threads (two 192-thread halves). [R7-validated,
// byte-identical]
// ---------------------------------------------------------------------------
__global__ __launch_bounds__(384)
void k_pool(const float* __restrict__ e1, const float* __restrict__ e2,
            const int* __restrict__ am,
            const float* __restrict__ s1, const float* __restrict__ s2,
            const int* __restrict__ iam,
            const float* __restrict__ hs, const int* __restrict__ st_,
            const int* __restrict__ en_,
            float* __restrict__ row_cls,
            float* __restrict__ sp_part, float* __restrict__ sp_cnt,
            float* __restrict__ sel_part, float* __restrict__ sel_cnt) {
  const int bid = blockIdx.x;
  const int t = threadIdx.x;
  const int half = t / 192;       // wave-uniform (waves 0-2 vs 3-5)
  const int tt = t % 192;
  __shared__ int   idxL[S2];
  __shared__ int   cntS;
  __shared__ float4 pf[192];      // half-1 partials for the combine

  if (bid < 512) {
    const int i = bid;
    if (t < 64) {
      const int m0 = am[i * S2 + t];
      const int m1 = am[i * S2 + 64 + t];
      const unsigned long long b0 = __ballot(m0 != 0);
      const unsigned long long b1 = __ballot(m1 != 0);
      const int c0 = (int)__popcll(b0);
      if (m0) idxL[(int)__popcll(b0 & ((1ULL << t) - 1))] = t;
      if (m1) idxL[c0 + (int)__popcll(b1 & ((1ULL << t) - 1))] = 64 + t;
      if (t == 0) cntS = c0 + (int)__popcll(b1);
    }
    __syncthreads();
    const int cnt = cntS;
    const int cntH = (cnt + 1 - half) >> 1;   // half0 ceil, half1 floor
    const float4* p1 = (const float4*)e1 + (size_t)i * (S2 * HV4) + tt;
    const float4* p2 = (const float4*)e2 + (size_t)i * (S2 * HV4) + tt;
    float ax = 0.f, ay = 0.f, az = 0.f, aw = 0.f;
    int kk = 0;
    for (; kk + 3 < cntH; kk += 4) {
      const int j0 = idxL[2 * kk + half];
      const int j1 = idxL[2 * (kk + 1) + half];
      const int j2 = idxL[2 * (kk + 2) + half];
      const int j3 = idxL[2 * (kk + 3) + half];
      float4 a0 = p1[j0 * HV4], b0 = p2[j0 * HV4];
      float4 a1 = p1[j1 * HV4], b1 = p2[j1 * HV4];
      float4 a2 = p1[j2 * HV4], b2 = p2[j2 * HV4];
      float4 a3 = p1[j3 * HV4], b3 = p2[j3 * HV4];
      ax += (a0.x + b0.x) + (a1.x + b1.x) + (a2.x + b2.x) + (a3.x + b3.x);
      ay += (a0.y + b0.y) + (a1.y + b1.y) + (a2.y + b2.y) + (a3.y + b3.y);
      az += (a0.z + b0.z) + (a1.z + b1.z) + (a2.z + b2.z) + (a3.z + b3.z);
      aw += (a0.w + b0.w) + (a1.w + b1.w) + (a2.w + b2.w) + (a3.w + b3.w);
    }
    for (; kk < cntH; ++kk) {
      const int j = idxL[2 * kk + half];
      float4 a = p1[j * HV4], b = p2[j * HV4];
      ax += a.x + b.x; ay += a.y + b.y; az += a.z + b.z; aw += a.w + b.w;
    }
    if (half == 1) { float4 o; o.x = ax; o.y = ay; o.z = az; o.w = aw; pf[tt] = o; }
    __syncthreads();
    if (half == 0) {
      const float inv = 1.f / (float)cnt;
      float4 o = pf[tt];
      o.x = (ax + o.x) * inv; o.y = (ay + o.y) * inv;
      o.z = (az + o.z) * inv; o.w = (aw + o.w) * inv;
      ((float4*)row_cls)[(size_t)i * HV4 + tt] = o;
    }
  } else if (bid < 1024) {
    const int blk = bid - 512;
    const int b = blk >> 5, c = blk & 31;
    if (t < 64) {
      const int m = (t < CH) ? iam[b * L + c * CH + t] : 0;
      const unsigned long long bm = __ballot(m != 0);
      if (m) idxL[(int)__popcll(bm & ((1ULL << t) - 1))] = t;
      if (t == 0) { const int cc = (int)__popcll(bm); cntS = cc; sp_cnt[blk] = (float)cc; }
    }
    __syncthreads();
    const int cnt = cntS;
    const int cntH = (cnt + 1 - half) >> 1;
    const float4* p1 = (const float4*)s1 + ((size_t)b * L + c * CH) * HV4 + tt;
    const float4* p2 = (const float4*)s2 + ((size_t)b * L + c * CH) * HV4 + tt;
    float ax = 0.f, ay = 0.f, az = 0.f, aw = 0.f;
    int kk = 0;
    for (; kk + 1 < cntH; kk += 2) {
      const int l0 = idxL[2 * kk + half];
      const int l1 = idxL[2 * (kk + 1) + half];
      float4 a0 = p1[l0 * HV4], b0 = p2[l0 * HV4];
      float4 a1 = p1[l1 * HV4], b1 = p2[l1 * HV4];
      ax += (a0.x + b0.x) + (a1.x + b1.x);
      ay += (a0.y + b0.y) + (a1.y + b1.y);
      az += (a0.z + b0.z) + (a1.z + b1.z);
      aw += (a0.w + b0.w) + (a1.w + b1.w);
    }
    for (; kk < cntH; ++kk) {
      const int l = idxL[2 * kk + half];
      float4 a = p1[l * HV4], b = p2[l * HV4];
      ax += a.x + b.x; ay += a.y + b.y; az += a.z + b.z; aw += a.w + b.w;
    }
    if (half == 1) { float4 o; o.x = ax; o.y = ay; o.z = az; o.w = aw; pf[tt] = o; }
    __syncthreads();
    if (half == 0) {
      float4 o = pf[tt];
      o.x += ax; o.y += ay; o.z += az; o.w += aw;
      ((float4*)sp_part)[(size_t)blk * HV4 + tt] = o;
    }
  } else {
    const int blk = bid - 1024;
    const int b = blk >> 5, c = blk & 31;
    const int st = st_[b], en = en_[b];
    const int lo = st > c * CH ? st : c * CH;
    const int hi = en < c * CH + CH ? en : c * CH + CH;
    const float4* p = (const float4*)hs + (size_t)b * L * HV4 + tt;
    float ax = 0.f, ay = 0.f, az = 0.f, aw = 0.f;
    for (int l = lo + half; l < hi; l += 2) {   // this half's rows, in-bounds
      float4 a0 = p[l * HV4];
      ax += a0.x; ay += a0.y; az += a0.z; aw += a0.w;
    }
    if (half == 1) { float4 o; o.x = ax; o.y = ay; o.z = az; o.w = aw; pf[tt] = o; }
    __syncthreads();
    if (half == 0) {
      float4 o = pf[tt];
      o.x += ax; o.y += ay; o.z += az; o.w += aw;
      ((float4*)sel_part)[(size_t)blk * HV4 + tt] = o;
      if (tt == 0) sel_cnt[blk] = (float)(hi > lo ? hi - lo : 0);
    }
  }
}

// ---------------------------------------------------------------------------
// K2: grid 16 + 192 = 208 blocks, 256 threads.
//   bid < 16 : sel combine + LayerNorm(gamma_s) -> sel_ln.  [R7-validated]
//   else     : q-tile = sp @ W_attn column tile (R7 pattern), then directly
//              emit SIM PARTIALS simp[b][ht][i] = sum_{h in tile} q[h]*rc[i,h]
//              (q never materialized; kills the separate attn_pool pass).
// ---------------------------------------------------------------------------
__global__ __launch_bounds__(256)
void k_mid(const float* __restrict__ sp_part, const float* __restrict__ sp_cnt,
           const float* __restrict__ sel_part, const float* __restrict__ sel_cnt,
           const float* __restrict__ W_attn, const float* __restrict__ rc,
           const float* __restrict__ gamma_s, const float* __restrict__ beta_s,
           float* __restrict__ sel_ln, float* __restrict__ simp) {
  __shared__ float spL[H];
  __shared__ float red[256];
  __shared__ float qt[64];
  const int bid = blockIdx.x, t = threadIdx.x;
  const int lane = t & 63, w = t >> 6;
  if (bid < B) {
    const int b = bid;
    float csel = 0.f;
    for (int c = 0; c < NCHUNK; ++c) csel += sel_cnt[b * NCHUNK + c];
    const float invc = 1.f / csel;
    float selv[3];
    #pragma unroll
    for (int k = 0; k < 3; ++k) {
      const int h = t + k * 256;
      float s = 0.f;
      for (int c = 0; c < NCHUNK; ++c)
        s += sel_part[((size_t)b * NCHUNK + c) * H + h];
      selv[k] = s * invc;
    }
    float s = selv[0] + selv[1] + selv[2];
    float ss = selv[0] * selv[0] + selv[1] * selv[1] + selv[2] * selv[2];
    #pragma unroll
    for (int off = 32; off > 0; off >>= 1) {
      s += __shfl_down(s, off);
      ss += __shfl_down(ss, off);
    }
    if (lane == 0) { red[w] = s; red[4 + w] = ss; }
    __syncthreads();
    const float S = red[0] + red[1] + red[2] + red[3];
    const float SS = red[4] + red[5] + red[6] + red[7];
    const float mu = S / (float)H;
    const float var = SS / (float)H - mu * mu;
    const float rstd = rsqrtf(var + 1e-12f);
    #pragma unroll
    for (int k = 0; k < 3; ++k) {
      const int h = t + k * 256;
      sel_ln[(size_t)b * H + h] = (selv[k] - mu) * rstd * gamma_s[h] + beta_s[h];
    }
  } else {
    const int qb = bid - B;             // 0..191
    const int b = qb / 12, ht = qb % 12;
    float csp = 0.f;
    for (int c = 0; c < NCHUNK; ++c) csp += sp_cnt[b * NCHUNK + c];
    const float inv = 1.f / csp;
    #pragma unroll
    for (int k = 0; k < 3; ++k) {
      const int h = t + k * 256;
      float a = 0.f;
      for (int c = 0; c < NCHUNK; ++c)
        a += sp_part[((size_t)b * NCHUNK + c) * H + h];
      spL[h] = a * inv;
    }
    __syncthreads();
    const int hl = t & 63, dseg = t >> 6;
    const float* wp = W_attn + (size_t)(dseg * 192) * H + ht * 64 + hl;
    const float* sv = spL + dseg * 192;
    float acc = 0.f;
    #pragma unroll 4
    for (int i = 0; i < 192; ++i) acc += sv[i] * wp[(size_t)i * H];
    red[t] = acc;
    __syncthreads();
    if (t < 64)
      qt[t] = red[t] + red[t + 64] + red[t + 128] + red[t + 192];
    __syncthreads();
    // sim partials: i = t>>3 (0..31), sub = t&7; 8 h's per thread
    const int i = t >> 3, sub = t & 7;
    const float* rr = rc + (size_t)(b * S1 + i) * H + ht * 64 + sub * 8;
    float p = qt[sub * 8 + 0] * rr[0] + qt[sub * 8 + 1] * rr[1]
            + qt[sub * 8 + 2] * rr[2] + qt[sub * 8 + 3] * rr[3]
            + qt[sub * 8 + 4] * rr[4] + qt[sub * 8 + 5] * rr[5]
            + qt[sub * 8 + 6] * rr[6] + qt[sub * 8 + 7] * rr[7];
    p += __shfl_down(p, 4);
    p += __shfl_down(p, 2);
    p += __shfl_down(p, 1);
    if (sub == 0) simp[((size_t)b * 12 + ht) * S1 + i] = p;
  }
}

// ---------------------------------------------------------------------------
// K3 (fused attn_pool + transform): grid 192 (b x 12 h-tiles), 256 threads.
//   reduce simp -> sims -> ragged softmax -> pooled[8][768] in LDS (96KB L2
//   reads of row_cls) -> barrier -> exact k_transform y-stripe GEMM.
// ---------------------------------------------------------------------------
__global__ __launch_bounds__(256)
void k_attn_tr(const float* __restrict__ simp, const float* __restrict__ rc,
               const int* __restrict__ extra_index,
               const float* __restrict__ W_t, const float* __restrict__ b_t,
               float* __restrict__ yb) {
  const int bid = blockIdx.x, t = threadIdx.x;
  const int b = bid / 12, hc = bid % 12;
  __shared__ float pL[NS * H];   // 24 KiB pooled
  __shared__ float simR[S1];
  __shared__ float w2L[S1];
  // sims: sum the 12 ht-partials (fixed order -> deterministic)
  if (t < S1) {
    float a = 0.f;
    for (int ht = 0; ht < 12; ++ht)
      a += simp[((size_t)b * 12 + ht) * S1 + t];
    simR[t] = a;
  }
  __syncthreads();
  if (t < NS) {
    const int vid = extra_index[b * NS + t];
    const float scale = 0.036084391824351615f;  // 1/sqrt(768)
    float x[M], mx = -1e30f;
    #pragma unroll
    for (int m = 0; m < M; ++m) {
      x[m] = (m < vid) ? simR[t * M + m] * scale : -1e30f;
      mx = fmaxf(mx, x[m]);
    }
    float s = 0.f, e[M];
    #pragma unroll
    for (int m = 0; m < M; ++m) { e[m] = expf(x[m] - mx); s += e[m]; }
    #pragma unroll
    for (int m = 0; m < M; ++m) w2L[t * M + m] = e[m] / s;
  }
  __syncthreads();
  // pooled[n][d] for all d (needed full-H for the y GEMM)
  #pragma unroll
  for (int k = 0; k < 3; ++k) {
    const int d = t + k * 256;
    #pragma unroll
    for (int n = 0; n < NS; ++n) {
      float p = 0.f;
      #pragma unroll
      for (int m = 0; m < M; ++m)
        p += w2L[n * M + m] * rc[(size_t)(b * S1 + n * M + m) * H + d];
      pL[n * H + d] = p;
    }
  }
  __syncthreads();
  // y-stripe GEMM [k_transform-identical]
  const int hl = t & 63;
  const int n0 = t >> 6;            // wave-uniform n -> LDS broadcast
  const int h = hc * 64 + hl;
  const float4* wr = (const float4*)(W_t + (size_t)h * H);
  const float4* pr0 = (const float4*)(pL + n0 * H);
  const float4* pr1 = (const float4*)(pL + (n0 + 4) * H);
  float acc0 = 0.f, acc1 = 0.f;
  #pragma unroll 4
  for (int d = 0; d < HV4; ++d) {
    float4 w = wr[d];
    float4 p0 = pr0[d], p1 = pr1[d];
    acc0 += w.x * p0.x + w.y * p0.y + w.z * p0.z + w.w * p0.w;
    acc1 += w.x * p1.x + w.y * p1.y + w.z * p1.z + w.w * p1.w;
  }
  const float bias = b_t[h];
  yb[((size_t)b * NS + n0) * H + h] = acc0 + bias;
  yb[((size_t)b * NS + n0 + 4) * H + h] = acc1 + bias;
}

// ---------------------------------------------------------------------------
// K4: fused row-LayerNorm + cosine score. [R7-validated, byte-identical]
// ---------------------------------------------------------------------------
__global__ __launch_bounds__(256)
void k_lnscore(const float* __restrict__ yb, const float* __restrict__ gamma,
               const float* __restrict__ beta, const float* __restrict__ sel_ln,
               float* __restrict__ out) {
  const int b = blockIdx.x, t = threadIdx.x;
  const int lane = t & 63, w = t >> 6;
  __shared__ float redS[NS * 4];
  __shared__ float redQ[NS * 4];
  float v[NS][3];
  for (int n = 0; n < NS; ++n) {
    float s = 0.f, ss = 0.f;
    #pragma unroll
    for (int k = 0; k < 3; ++k) {
      const float x = yb[((size_t)b * NS + n) * H + t + k * 256];
      v[n][k] = x; s += x; ss += x * x;
    }
    #pragma unroll
    for (int off = 32; off > 0; off >>= 1) {
      s += __shfl_down(s, off);
      ss += __shfl_down(ss, off);
    }
    if (lane == 0) { redS[n * 4 + w] = s; redQ[n * 4 + w] = ss; }
  }
  __syncthreads();
  float g[3], be[3];
  #pragma unroll
  for (int k = 0; k < 3; ++k) { g[k] = gamma[t + k * 256]; be[k] = beta[t + k * 256]; }
  float S[3] = {0.f, 0.f, 0.f}, SS[3] = {0.f, 0.f, 0.f};
  for (int n = 0; n < NS; ++n) {
    const float Sn = redS[n * 4] + redS[n * 4 + 1] + redS[n * 4 + 2] + redS[n * 4 + 3];
    const float Qn = redQ[n * 4] + redQ[n * 4 + 1] + redQ[n * 4 + 2] + redQ[n * 4 + 3];
    const float mu = Sn / (float)H;
    const float var = Qn / (float)H - mu * mu;
    const float rstd = rsqrtf(var + 1e-12f);
    #pragma unroll
    for (int k = 0; k < 3; ++k) {
      const float c = (v[n][k] - mu) * rstd * g[k] + be[k];
      S[k] += c; SS[k] += c * c;
    }
  }
  #pragma unroll
  for (int k = 0; k < 3; ++k) {
    const int h = t + k * 256;
    const float sl = sel_ln[(size_t)b * H + h];
    const float n1 = 2.8284271247461903f * fabsf(sl);  // sqrt(8)*|sel|
    const float n2 = sqrtf(SS[k]);
    out[(size_t)b * H + h] = sl * S[k] / (fmaxf(n1, 1e-8f) * fmaxf(n2, 1e-8f));
  }
}

// ---------------------------------------------------------------------------
extern "C" void kernel_launch(void* const* d_in, const int* in_sizes, int n_in,
                              void* d_out, int out_size, void* d_ws, size_t ws_size,
                              hipStream_t stream) {
  const float* hidden_states = (const float*)d_in[0];
  const float* sent_h1       = (const float*)d_in[1];
  const float* sent_h2       = (const float*)d_in[2];
  const int*   attention_mask= (const int*)  d_in[3];
  const float* expl_h1       = (const float*)d_in[4];
  const float* expl_h2       = (const float*)d_in[5];
  const int*   extra_am      = (const int*)  d_in[6];
  const int*   extra_index   = (const int*)  d_in[7];
  const int*   extra_start   = (const int*)  d_in[8];
  const int*   extra_end     = (const int*)  d_in[9];
  const float* W_attn        = (const float*)d_in[10];
  const float* W_t           = (const float*)d_in[11];
  const float* b_t           = (const float*)d_in[12];
  const float* gamma_t       = (const float*)d_in[13];
  const float* beta_t        = (const float*)d_in[14];
  const float* gamma_s       = (const float*)d_in[15];
  const float* beta_s        = (const float*)d_in[16];
  float* out = (float*)d_out;

  float* ws = (float*)d_ws;
  float* row_cls  = ws;                        // 512*768
  float* sp_part  = row_cls + 512 * H;         // 512*768
  float* sp_cnt   = sp_part + 512 * H;         // 512
  float* sel_part = sp_cnt + 512;              // 512*768
  float* sel_cnt  = sel_part + 512 * H;        // 512
  float* sel_ln   = sel_cnt + 512;             // 16*768
  float* simp     = sel_ln + B * H;            // 16*12*32
  float* yb       = simp + B * 12 * S1;        // 128*768

  k_pool<<<1536, 384, 0, stream>>>(expl_h1, expl_h2, extra_am,
                                   sent_h1, sent_h2, attention_mask,
                                   hidden_states, extra_start, extra_end,
                                   row_cls, sp_part, sp_cnt, sel_part, sel_cnt);
  k_mid<<<B + 192, 256, 0, stream>>>(sp_part, sp_cnt, sel_part, sel_cnt,
                                     W_attn, row_cls, gamma_s, beta_s,
                                     sel_ln, simp);
  k_attn_tr<<<192, 256, 0, stream>>>(simp, row_cls, extra_index, W_t, b_t, yb);
  k_lnscore<<<B, 256, 0, stream>>>(yb, gamma_t, beta_t, sel_ln, out);
}